// Round 10
// baseline (103.901 us; speedup 1.0000x reference)
//
#include <hip/hip_runtime.h>
#include <stdint.h>

#define DIM   128
#define MN    1024
#define BATCH 2048
#define ALPHA 0.3f
#define SIGMA 16.0f
#define LOG2E 1.44269504088896f

typedef _Float16 half8 __attribute__((ext_vector_type(8)));
typedef _Float16 half4 __attribute__((ext_vector_type(4)));
typedef float    floatx4 __attribute__((ext_vector_type(4)));

// ws layout (bytes):
//   S    f32[1024][128]  @ 0        (512 KB)
//   cnt  f32[1024]       @ 524288   (4 KB)     (S+cnt zeroed as one range)
//   w2   f32[1024]       @ 528384   (4 KB)
//   wh   f16[1024][128]  @ 532480   (256 KB)
//   wl   f16[1024][128]  @ 794624   (256 KB)

// ---------------------------------------------------------------------------
// Kernel 1: prep. blocks 0..7: w -> f16 hi/lo split + w2 (hi+lo carries ~22
// mantissa bits => 3-product MFMA dot is fp32-grade). blocks 8..136: zero
// S+cnt (33024 float4 exactly).
// ---------------------------------------------------------------------------
__global__ __launch_bounds__(256) void prep_kernel(
    const float* __restrict__ w, float* __restrict__ w2,
    _Float16* __restrict__ wh, _Float16* __restrict__ wl,
    float4* __restrict__ Sq)
{
  const int t = threadIdx.x;
  const int bid = blockIdx.x;
  if (bid < 8) {                       // w: 2048 threads, half-row each + w2
    int idx = bid * 256 + t;
    int row = idx >> 1, half = idx & 1;
    int base = row * DIM + half * 64;
    float s = 0.f;
#pragma unroll
    for (int q = 0; q < 16; ++q) {
      float4 v = *reinterpret_cast<const float4*>(&w[base + q * 4]);
      s += v.x * v.x + v.y * v.y + v.z * v.z + v.w * v.w;
      half4 h, l;
      h[0] = (_Float16)v.x; l[0] = (_Float16)(v.x - (float)h[0]);
      h[1] = (_Float16)v.y; l[1] = (_Float16)(v.y - (float)h[1]);
      h[2] = (_Float16)v.z; l[2] = (_Float16)(v.z - (float)h[2]);
      h[3] = (_Float16)v.w; l[3] = (_Float16)(v.w - (float)h[3]);
      *reinterpret_cast<half4*>(&wh[base + q * 4]) = h;
      *reinterpret_cast<half4*>(&wl[base + q * 4]) = l;
    }
    s += __shfl_xor(s, 1);
    if (!half) w2[row] = s;
  } else {                             // zero S + cnt: 129 blocks x 256
    int i = (bid - 8) * 256 + t;       // 33024 float4 = 516 KB
    Sq[i] = make_float4(0.f, 0.f, 0.f, 0.f);
  }
}

// ---------------------------------------------------------------------------
// Kernel 2: BMU + scatter (fused). 128 blocks x 1024 thr (16 waves, 4/SIMD).
// Block owns 16 batches; wave wv sweeps units wv*64..wv*64+63 (4 u-tiles).
// B-frag (x): f32->f16 hi/lo IN-REGISTER per lane. A-frag (w) streamed from
// wh/wl as 16B contiguous loads. 12 MFMA per u-tile (3-product split).
// C/D: col(batch)=lane&15, row(unit)=quad*4+reg  [established R5-R9].
// Argmin in-block: shfl over quads -> kb[wave][16] -> min over 16 waves.
// Scatter (t<512): S[v] += x[b], cnt[v] += 1, v = argmin. S zeroed by prep.
// ---------------------------------------------------------------------------
__global__ __launch_bounds__(1024) void bmu_scatter_kernel(
    const float* __restrict__ x, const float* __restrict__ w2,
    const _Float16* __restrict__ wh, const _Float16* __restrict__ wl,
    float* __restrict__ S, float* __restrict__ cnt)
{
  __shared__ unsigned long long kb[16][16];
  __shared__ unsigned long long fkey[16];

  const int t    = threadIdx.x;
  const int lane = t & 63;
  const int wv   = t >> 6;            // 16 waves
  const int b0   = blockIdx.x * 16;
  const int r    = lane & 15;
  const int q    = lane >> 4;

  // B-frags from x, in-register hi/lo split
  half8 Bh[4], Bl[4];
  {
    const float* xr = x + (b0 + r) * DIM + q * 8;
#pragma unroll
    for (int c = 0; c < 4; ++c) {
      float4 v0 = *reinterpret_cast<const float4*>(xr + c * 32);
      float4 v1 = *reinterpret_cast<const float4*>(xr + c * 32 + 4);
      float xs[8] = {v0.x, v0.y, v0.z, v0.w, v1.x, v1.y, v1.z, v1.w};
#pragma unroll
      for (int j = 0; j < 8; ++j) {
        _Float16 h = (_Float16)xs[j];
        Bh[c][j] = h;
        Bl[c][j] = (_Float16)(xs[j] - (float)h);
      }
    }
  }

  unsigned long long kmin = ~0ull;
#pragma unroll 2
  for (int ut = 0; ut < 4; ++ut) {
    const int u0 = wv * 64 + ut * 16;
    const _Float16* wrh = wh + (u0 + r) * DIM + q * 8;
    const _Float16* wrl = wl + (u0 + r) * DIM + q * 8;
    half8 Ah[4], Al[4];
#pragma unroll
    for (int c = 0; c < 4; ++c) {
      Ah[c] = *reinterpret_cast<const half8*>(wrh + c * 32);
      Al[c] = *reinterpret_cast<const half8*>(wrl + c * 32);
    }
    floatx4 acc = {0.f, 0.f, 0.f, 0.f};
#pragma unroll
    for (int c = 0; c < 4; ++c) {
      acc = __builtin_amdgcn_mfma_f32_16x16x32_f16(Ah[c], Bh[c], acc, 0, 0, 0);
      acc = __builtin_amdgcn_mfma_f32_16x16x32_f16(Ah[c], Bl[c], acc, 0, 0, 0);
      acc = __builtin_amdgcn_mfma_f32_16x16x32_f16(Al[c], Bh[c], acc, 0, 0, 0);
    }
    float4 w2q = *reinterpret_cast<const float4*>(&w2[u0 + q * 4]);
    float w2a[4] = {w2q.x, w2q.y, w2q.z, w2q.w};
#pragma unroll
    for (int i = 0; i < 4; ++i) {
      float s = w2a[i] - 2.0f * acc[i];
      unsigned int sb = __float_as_uint(s);
      sb ^= (sb >> 31) ? 0xFFFFFFFFu : 0x80000000u;   // total order
      unsigned long long key =
          ((unsigned long long)sb << 32) | (unsigned int)(u0 + q * 4 + i);
      if (key < kmin) kmin = key;
    }
  }
  // reduce over quads (units), then across waves
  unsigned long long o;
  o = __shfl_xor(kmin, 16); if (o < kmin) kmin = o;
  o = __shfl_xor(kmin, 32); if (o < kmin) kmin = o;
  if (lane < 16) kb[wv][r] = kmin;
  __syncthreads();
  if (t < 16) {
    unsigned long long m = kb[0][t];
#pragma unroll
    for (int k = 1; k < 16; ++k)
      if (kb[k][t] < m) m = kb[k][t];
    fkey[t] = m;
  }
  __syncthreads();

  // scatter: threads 0..511 = 16 batches x 32 quads
  if (t < 512) {
    int bl = t >> 5, cq = t & 31;
    unsigned int v = (unsigned int)fkey[bl];         // low 32 = argmin unit
    float4 xv = *reinterpret_cast<const float4*>(&x[(b0 + bl) * DIM + cq * 4]);
    float* Sv = S + v * DIM + cq * 4;
    unsafeAtomicAdd(&Sv[0], xv.x);
    unsafeAtomicAdd(&Sv[1], xv.y);
    unsafeAtomicAdd(&Sv[2], xv.z);
    unsafeAtomicAdd(&Sv[3], xv.w);
    if (cq == 0) unsafeAtomicAdd(&cnt[v], 1.0f);
  }
}

// ---------------------------------------------------------------------------
// Kernel 3: separable-Gaussian conv + finalize. 256 blocks x 512 thr.
// Key fact: pass 2 (over vy) for output column ux needs only pass 1's same
// column => block = (channel quad q, ux-group of 4) closes both passes.
// Block bid: q = bid >> 3, uxg = bid & 7; thread: ui = t>>7 (ux = uxg*4+ui),
// vy/uy = (t&127)>>2, j = t&3.
//   pass1: T1[ui][vy][j] = sum_vx gx[ux-vx] * S[(vy*32+vx)*128 + q*4 + j]
//          Tcc[ui][vy]   = sum_vx gx[ux-vx] * cnt[vy*32+vx]      (j==0)
//   pass2: delta = sum_vy gy[uy-vy] * T1[ui][vy][j]; rowsum likewise;
//          out = w*(1-rowsum) + delta.
// ---------------------------------------------------------------------------
__global__ __launch_bounds__(512) void convfinal_kernel(
    const float* __restrict__ S, const float* __restrict__ cnt,
    const float* __restrict__ w, const int* __restrict__ itp,
    float* __restrict__ out)
{
  __shared__ float gxt[64], gyt[64];
  __shared__ float T1[4][32][4];
  __shared__ float Tcc[4][32];

  const int t   = threadIdx.x;
  const int q   = blockIdx.x >> 3;
  const int uxg = blockIdx.x & 7;
  const int ui  = t >> 7;
  const int ux  = uxg * 4 + ui;
  const int rem = t & 127;
  const int vy  = rem >> 2;           // also uy in pass 2
  const int j   = rem & 3;

  const float lr_decay = 1.0f - (float)itp[0] * 0.01f;
  const float alpha_op = ALPHA * lr_decay;
  const float sg       = SIGMA * lr_decay;
  const float c2       = -LOG2E / (sg * sg);

  if (t < 63) {
    float dd = (float)(t - 31);
    float g = __builtin_amdgcn_exp2f(c2 * dd * dd);
    gxt[t] = g;
    gyt[t] = alpha_op * g;             // fold alpha into pass 2
  }
  __syncthreads();

  // pass 1 (over vx)
  {
    float a = 0.f, ac = 0.f;
    const float* Sp = S + (vy * 32) * DIM + q * 4 + j;
    const float* Cp = cnt + vy * 32;
#pragma unroll 8
    for (int vx = 0; vx < 32; ++vx) {
      float g = gxt[ux - vx + 31];
      a = fmaf(g, Sp[vx * DIM], a);
      if (j == 0) ac = fmaf(g, Cp[vx], ac);
    }
    T1[ui][vy][j] = a;
    if (j == 0) Tcc[ui][vy] = ac;
  }
  __syncthreads();

  // pass 2 (over vy) + finalize; reuse vy index as uy
  {
    const int uy = vy;
    float d = 0.f, rs = 0.f;
#pragma unroll 8
    for (int v = 0; v < 32; ++v) {
      float g = gyt[uy - v + 31];
      d  = fmaf(g, T1[ui][v][j], d);
      rs = fmaf(g, Tcc[ui][v], rs);
    }
    int p = (uy * 32 + ux) * DIM + q * 4 + j;
    out[p] = w[p] * (1.0f - rs) + d;
  }
}

extern "C" void kernel_launch(void* const* d_in, const int* in_sizes, int n_in,
                              void* d_out, int out_size, void* d_ws, size_t ws_size,
                              hipStream_t stream) {
  const float* x   = (const float*)d_in[0];   // [2048,128] f32
  const float* w   = (const float*)d_in[1];   // [1024,128] f32
  const int*   itp = (const int*)d_in[3];     // [1] i32 (meshgrid baked in)
  float* out = (float*)d_out;                 // [1024,128] f32

  char* ws = (char*)d_ws;
  float*     S   = (float*)ws;                // 512 KB
  float*     cnt = (float*)(ws + 524288);     //   4 KB
  float*     w2  = (float*)(ws + 528384);     //   4 KB
  _Float16*  wh  = (_Float16*)(ws + 532480);  // 256 KB
  _Float16*  wl  = (_Float16*)(ws + 794624);  // 256 KB

  prep_kernel<<<137, 256, 0, stream>>>(w, w2, wh, wl, (float4*)S);
  bmu_scatter_kernel<<<128, 1024, 0, stream>>>(x, w2, wh, wl, S, cnt);
  convfinal_kernel<<<256, 512, 0, stream>>>(S, cnt, w, itp, out);
}

// Round 11
// 95.172 us; speedup vs baseline: 1.0917x; 1.0917x over previous
//
#include <hip/hip_runtime.h>
#include <stdint.h>

#define DIM   128
#define MN    1024
#define BATCH 2048
#define ALPHA 0.3f
#define SIGMA 16.0f
#define LOG2E 1.44269504088896f

typedef _Float16 half8 __attribute__((ext_vector_type(8)));
typedef float    floatx4 __attribute__((ext_vector_type(4)));

// ws layout: keys u32[2048] @ 0 (8 KB). That's all.

// ---------------------------------------------------------------------------
// Kernel 1: BMU. 128 blocks x 1024 thr (16 waves, 4/SIMD). Block owns 16
// batches; wave wv sweeps units wv*64..wv*64+63 (4 u-tiles of 16).
// BOTH operands converted f32 -> f16 hi/lo IN-REGISTER per lane (each lane
// loads/converts exactly its fragment elements; hi+lo carries ~22 mantissa
// bits so the 3-product MFMA dot is fp32-grade; lolo term ~2^-22 dropped).
// w2 computed in-wave: lane sums squares of its 32 A-elements, shfl_xor
// 16/32 completes the 128-dim row sum (lanes with same r=unit-row), then
// __shfl redistributes to the C/D epilogue mapping (row=q*4+i).
// C/D: col(batch)=lane&15, row(unit)=quad*4+reg  [established R5-R10].
// Argmin in-block (shfl quads -> kb[16][16] -> min over waves) -> plain
// u32 store to keys. No workspace init, no atomics, no prep kernel.
// ---------------------------------------------------------------------------
__global__ __launch_bounds__(1024) void bmu_kernel(
    const float* __restrict__ x, const float* __restrict__ w,
    unsigned int* __restrict__ keys)
{
  __shared__ unsigned long long kb[16][16];

  const int t    = threadIdx.x;
  const int lane = t & 63;
  const int wv   = t >> 6;            // 16 waves
  const int b0   = blockIdx.x * 16;
  const int r    = lane & 15;
  const int q    = lane >> 4;

  // B-frags from x, in-register hi/lo split
  half8 Bh[4], Bl[4];
  {
    const float* xr = x + (b0 + r) * DIM + q * 8;
#pragma unroll
    for (int c = 0; c < 4; ++c) {
      float4 v0 = *reinterpret_cast<const float4*>(xr + c * 32);
      float4 v1 = *reinterpret_cast<const float4*>(xr + c * 32 + 4);
      float xs[8] = {v0.x, v0.y, v0.z, v0.w, v1.x, v1.y, v1.z, v1.w};
#pragma unroll
      for (int j = 0; j < 8; ++j) {
        _Float16 h = (_Float16)xs[j];
        Bh[c][j] = h;
        Bl[c][j] = (_Float16)(xs[j] - (float)h);
      }
    }
  }

  unsigned long long kmin = ~0ull;
#pragma unroll 2
  for (int ut = 0; ut < 4; ++ut) {
    const int u0 = wv * 64 + ut * 16;
    // A-frags from w, in-register hi/lo split + w2 partial (32 dims/lane)
    half8 Ah[4], Al[4];
    float w2p = 0.f;
    {
      const float* wr = w + (u0 + r) * DIM + q * 8;
#pragma unroll
      for (int c = 0; c < 4; ++c) {
        float4 v0 = *reinterpret_cast<const float4*>(wr + c * 32);
        float4 v1 = *reinterpret_cast<const float4*>(wr + c * 32 + 4);
        float wsb[8] = {v0.x, v0.y, v0.z, v0.w, v1.x, v1.y, v1.z, v1.w};
#pragma unroll
        for (int j = 0; j < 8; ++j) {
          float vv = wsb[j];
          w2p = fmaf(vv, vv, w2p);
          _Float16 h = (_Float16)vv;
          Ah[c][j] = h;
          Al[c][j] = (_Float16)(vv - (float)h);
        }
      }
    }
    // complete the 128-dim |w|^2 across the 4 q-lanes sharing unit-row r
    w2p += __shfl_xor(w2p, 16);
    w2p += __shfl_xor(w2p, 32);

    floatx4 acc = {0.f, 0.f, 0.f, 0.f};
#pragma unroll
    for (int c = 0; c < 4; ++c) {
      acc = __builtin_amdgcn_mfma_f32_16x16x32_f16(Ah[c], Bh[c], acc, 0, 0, 0);
      acc = __builtin_amdgcn_mfma_f32_16x16x32_f16(Ah[c], Bl[c], acc, 0, 0, 0);
      acc = __builtin_amdgcn_mfma_f32_16x16x32_f16(Al[c], Bh[c], acc, 0, 0, 0);
    }
#pragma unroll
    for (int i = 0; i < 4; ++i) {
      // w2 for unit-row q*4+i lives in lane q*4+i (any quad) after reduce
      float w2v = __shfl(w2p, q * 4 + i);
      float s = w2v - 2.0f * acc[i];
      unsigned int sb = __float_as_uint(s);
      sb ^= (sb >> 31) ? 0xFFFFFFFFu : 0x80000000u;   // total order
      unsigned long long key =
          ((unsigned long long)sb << 32) | (unsigned int)(u0 + q * 4 + i);
      if (key < kmin) kmin = key;
    }
  }
  // reduce over quads (units), then across waves; plain store (no init dep)
  unsigned long long o;
  o = __shfl_xor(kmin, 16); if (o < kmin) kmin = o;
  o = __shfl_xor(kmin, 32); if (o < kmin) kmin = o;
  if (lane < 16) kb[wv][r] = kmin;
  __syncthreads();
  if (t < 16) {
    unsigned long long m = kb[0][t];
#pragma unroll
    for (int k = 1; k < 16; ++k)
      if (kb[k][t] < m) m = kb[k][t];
    keys[b0 + t] = (unsigned int)m;               // low 32 = argmin unit
  }
}

// ---------------------------------------------------------------------------
// Kernel 2: LDS-binned gather + separable conv + finalize. 256 blocks x 512.
// Block = (channel quad q = bid>>3, ux-group uxg = bid&7).
// Stage 1: bin all 2048 batches into LDS by BMU grid cell:
//   bin[j][vy][vx] += x[b][q*4+j], cntl[vy][vx] += 1   (ds_add_f32 atomics)
// Skewed layout: plane stride 1064 (=33*32+8), row stride 33 => all LDS
// aliasing <=2-way (free). Stage 2: conv pass 1 over vx -> T1/Tcc; pass 2
// over vy + finalize: out = w*(1-rowsum) + delta. Replaces the global
// scatter kernel AND the S/cnt zeroing (no workspace needed).
// ---------------------------------------------------------------------------
#define PLANE 1064                    // 32*33 + 8: bank-skew between j-planes
__global__ __launch_bounds__(512) void convgather_kernel(
    const float* __restrict__ x, const unsigned int* __restrict__ keys,
    const float* __restrict__ w, const int* __restrict__ itp,
    float* __restrict__ out)
{
  __shared__ float bin[4 * PLANE + 32 * 33];   // 4 S-planes + cnt plane
  __shared__ float gxt[64], gyt[64];
  __shared__ float T1[4][32][4];
  __shared__ float Tcc[4][32];

  const int t   = threadIdx.x;
  const int q   = blockIdx.x >> 3;
  const int uxg = blockIdx.x & 7;

  // zero bins
  for (int i = t; i < 4 * PLANE + 32 * 33; i += 512) bin[i] = 0.f;

  const float lr_decay = 1.0f - (float)itp[0] * 0.01f;
  const float alpha_op = ALPHA * lr_decay;
  const float sg       = SIGMA * lr_decay;
  const float c2       = -LOG2E / (sg * sg);
  if (t < 63) {
    float dd = (float)(t - 31);
    float g = __builtin_amdgcn_exp2f(c2 * dd * dd);
    gxt[t] = g;
    gyt[t] = alpha_op * g;             // fold alpha into pass 2
  }
  __syncthreads();

  // bin 2048 batches: 4 per thread
#pragma unroll
  for (int s = 0; s < 4; ++s) {
    int b = s * 512 + t;
    unsigned int v = keys[b];
    int vy = v >> 5, vx = v & 31;
    float4 xv = *reinterpret_cast<const float4*>(&x[b * DIM + q * 4]);
    int base = vy * 33 + vx;
    atomicAdd(&bin[0 * PLANE + base], xv.x);
    atomicAdd(&bin[1 * PLANE + base], xv.y);
    atomicAdd(&bin[2 * PLANE + base], xv.z);
    atomicAdd(&bin[3 * PLANE + base], xv.w);
    atomicAdd(&bin[4 * PLANE + base], 1.0f);
  }
  __syncthreads();

  const int ui  = t >> 7;              // 0..3 -> ux = uxg*4+ui
  const int ux  = uxg * 4 + ui;
  const int rem = t & 127;
  const int vy  = rem >> 2;            // also uy in pass 2
  const int j   = rem & 3;

  // pass 1 (over vx), read from LDS bins
  {
    float a = 0.f, ac = 0.f;
    const float* Sp = bin + j * PLANE + vy * 33;
    const float* Cp = bin + 4 * PLANE + vy * 33;
#pragma unroll 8
    for (int vx = 0; vx < 32; ++vx) {
      float g = gxt[ux - vx + 31];
      a = fmaf(g, Sp[vx], a);
      if (j == 0) ac = fmaf(g, Cp[vx], ac);
    }
    T1[ui][vy][j] = a;
    if (j == 0) Tcc[ui][vy] = ac;
  }
  __syncthreads();

  // pass 2 (over vy) + finalize
  {
    const int uy = vy;
    float d = 0.f, rs = 0.f;
#pragma unroll 8
    for (int v = 0; v < 32; ++v) {
      float g = gyt[uy - v + 31];
      d  = fmaf(g, T1[ui][v][j], d);
      rs = fmaf(g, Tcc[ui][v], rs);
    }
    int p = (uy * 32 + ux) * DIM + q * 4 + j;
    out[p] = w[p] * (1.0f - rs) + d;
  }
}

extern "C" void kernel_launch(void* const* d_in, const int* in_sizes, int n_in,
                              void* d_out, int out_size, void* d_ws, size_t ws_size,
                              hipStream_t stream) {
  const float* x   = (const float*)d_in[0];   // [2048,128] f32
  const float* w   = (const float*)d_in[1];   // [1024,128] f32
  const int*   itp = (const int*)d_in[3];     // [1] i32 (meshgrid baked in)
  float* out = (float*)d_out;                 // [1024,128] f32

  unsigned int* keys = (unsigned int*)d_ws;   // 8 KB, fully written by K1

  bmu_kernel<<<128, 1024, 0, stream>>>(x, w, keys);
  convgather_kernel<<<256, 512, 0, stream>>>(x, keys, w, itp, out);
}

// Round 12
// 87.917 us; speedup vs baseline: 1.1818x; 1.0825x over previous
//
#include <hip/hip_runtime.h>
#include <stdint.h>

#define DIM   128
#define MN    1024
#define BATCH 2048
#define ALPHA 0.3f
#define SIGMA 16.0f
#define LOG2E 1.44269504088896f

typedef _Float16 half8 __attribute__((ext_vector_type(8)));
typedef float    floatx4 __attribute__((ext_vector_type(4)));

// ws layout: keys u64[2][2048] @ 0 (32 KB). Half h covers units [h*512,(h+1)*512).

// ---------------------------------------------------------------------------
// Kernel 1: BMU. 256 blocks x 1024 thr (16 waves, 4/SIMD) — full chip.
// Block = (batch-group bg = bid>>1 : 16 batches, half h = bid&1 : 512 units).
// Wave wv sweeps units h*512 + wv*32 .. +31 (2 u-tiles of 16).
// BOTH operands converted f32 -> f16 hi/lo IN-REGISTER per lane (hi+lo
// carries ~22 mantissa bits => 3-product MFMA dot is fp32-grade; lolo
// ~2^-22 dropped). w2 in-wave via shfl_xor 16/32 + __shfl redistribute.
// C/D: col(batch)=lane&15, row(unit)=quad*4+reg  [established R5-R11].
// Argmin in-block (shfl quads -> kb[16][16] -> min over waves) -> plain
// u64 store keys[h][b] (score|unit). No init, no atomics. convgather
// min-combines the two halves (unit in low bits => first-index tie-break
// preserved: disjoint ascending unit ranges).
// ---------------------------------------------------------------------------
__global__ __launch_bounds__(1024) void bmu_kernel(
    const float* __restrict__ x, const float* __restrict__ w,
    unsigned long long* __restrict__ keys)
{
  __shared__ unsigned long long kb[16][16];

  const int t    = threadIdx.x;
  const int lane = t & 63;
  const int wv   = t >> 6;            // 16 waves
  const int b0   = (blockIdx.x >> 1) * 16;
  const int h    = blockIdx.x & 1;
  const int r    = lane & 15;
  const int q    = lane >> 4;

  // B-frags from x, in-register hi/lo split
  half8 Bh[4], Bl[4];
  {
    const float* xr = x + (b0 + r) * DIM + q * 8;
#pragma unroll
    for (int c = 0; c < 4; ++c) {
      float4 v0 = *reinterpret_cast<const float4*>(xr + c * 32);
      float4 v1 = *reinterpret_cast<const float4*>(xr + c * 32 + 4);
      float xs[8] = {v0.x, v0.y, v0.z, v0.w, v1.x, v1.y, v1.z, v1.w};
#pragma unroll
      for (int j = 0; j < 8; ++j) {
        _Float16 hh = (_Float16)xs[j];
        Bh[c][j] = hh;
        Bl[c][j] = (_Float16)(xs[j] - (float)hh);
      }
    }
  }

  unsigned long long kmin = ~0ull;
#pragma unroll
  for (int ut = 0; ut < 2; ++ut) {
    const int u0 = h * 512 + wv * 32 + ut * 16;
    // A-frags from w, in-register hi/lo split + w2 partial (32 dims/lane)
    half8 Ah[4], Al[4];
    float w2p = 0.f;
    {
      const float* wr = w + (u0 + r) * DIM + q * 8;
#pragma unroll
      for (int c = 0; c < 4; ++c) {
        float4 v0 = *reinterpret_cast<const float4*>(wr + c * 32);
        float4 v1 = *reinterpret_cast<const float4*>(wr + c * 32 + 4);
        float wsb[8] = {v0.x, v0.y, v0.z, v0.w, v1.x, v1.y, v1.z, v1.w};
#pragma unroll
        for (int j = 0; j < 8; ++j) {
          float vv = wsb[j];
          w2p = fmaf(vv, vv, w2p);
          _Float16 hh = (_Float16)vv;
          Ah[c][j] = hh;
          Al[c][j] = (_Float16)(vv - (float)hh);
        }
      }
    }
    // complete the 128-dim |w|^2 across the 4 q-lanes sharing unit-row r
    w2p += __shfl_xor(w2p, 16);
    w2p += __shfl_xor(w2p, 32);

    floatx4 acc = {0.f, 0.f, 0.f, 0.f};
#pragma unroll
    for (int c = 0; c < 4; ++c) {
      acc = __builtin_amdgcn_mfma_f32_16x16x32_f16(Ah[c], Bh[c], acc, 0, 0, 0);
      acc = __builtin_amdgcn_mfma_f32_16x16x32_f16(Ah[c], Bl[c], acc, 0, 0, 0);
      acc = __builtin_amdgcn_mfma_f32_16x16x32_f16(Al[c], Bh[c], acc, 0, 0, 0);
    }
#pragma unroll
    for (int i = 0; i < 4; ++i) {
      // w2 for unit-row q*4+i lives in lane q*4+i (any quad) after reduce
      float w2v = __shfl(w2p, q * 4 + i);
      float s = w2v - 2.0f * acc[i];
      unsigned int sb = __float_as_uint(s);
      sb ^= (sb >> 31) ? 0xFFFFFFFFu : 0x80000000u;   // total order
      unsigned long long key =
          ((unsigned long long)sb << 32) | (unsigned int)(u0 + q * 4 + i);
      if (key < kmin) kmin = key;
    }
  }
  // reduce over quads (units), then across waves; plain store (no init dep)
  unsigned long long o;
  o = __shfl_xor(kmin, 16); if (o < kmin) kmin = o;
  o = __shfl_xor(kmin, 32); if (o < kmin) kmin = o;
  if (lane < 16) kb[wv][r] = kmin;
  __syncthreads();
  if (t < 16) {
    unsigned long long m = kb[0][t];
#pragma unroll
    for (int k = 1; k < 16; ++k)
      if (kb[k][t] < m) m = kb[k][t];
    keys[h * BATCH + b0 + t] = m;
  }
}

// ---------------------------------------------------------------------------
// Kernel 2: LDS-binned gather + separable conv + finalize. 256 blocks x 512.
// Block = (channel quad q = bid>>3, ux-group uxg = bid&7).
// Stage 1: v = unit of min(keysA[b], keysB[b]); bin into LDS by grid cell:
//   bin[j][vy][vx] += x[b][q*4+j], cnt[vy][vx] += 1   (ds_add_f32 atomics)
// Skewed layout: plane stride 1064 (=33*32+8), row stride 33 => all LDS
// aliasing <=2-way (free). Stage 2: conv pass 1 over vx -> T1/Tcc; pass 2
// over vy + finalize: out = w*(1-rowsum) + delta.
// ---------------------------------------------------------------------------
#define PLANE 1064                    // 32*33 + 8: bank-skew between j-planes
__global__ __launch_bounds__(512) void convgather_kernel(
    const float* __restrict__ x, const unsigned long long* __restrict__ keys,
    const float* __restrict__ w, const int* __restrict__ itp,
    float* __restrict__ out)
{
  __shared__ float bin[4 * PLANE + 32 * 33];   // 4 S-planes + cnt plane
  __shared__ float gxt[64], gyt[64];
  __shared__ float T1[4][32][4];
  __shared__ float Tcc[4][32];

  const int t   = threadIdx.x;
  const int q   = blockIdx.x >> 3;
  const int uxg = blockIdx.x & 7;

  // zero bins
  for (int i = t; i < 4 * PLANE + 32 * 33; i += 512) bin[i] = 0.f;

  const float lr_decay = 1.0f - (float)itp[0] * 0.01f;
  const float alpha_op = ALPHA * lr_decay;
  const float sg       = SIGMA * lr_decay;
  const float c2       = -LOG2E / (sg * sg);
  if (t < 63) {
    float dd = (float)(t - 31);
    float g = __builtin_amdgcn_exp2f(c2 * dd * dd);
    gxt[t] = g;
    gyt[t] = alpha_op * g;             // fold alpha into pass 2
  }
  __syncthreads();

  // bin 2048 batches: 4 per thread; min-combine the two half-keys
#pragma unroll
  for (int s = 0; s < 4; ++s) {
    int b = s * 512 + t;
    unsigned long long kA = keys[b];
    unsigned long long kB = keys[BATCH + b];
    unsigned int v = (unsigned int)(kA < kB ? kA : kB);
    int vy = v >> 5, vx = v & 31;
    float4 xv = *reinterpret_cast<const float4*>(&x[b * DIM + q * 4]);
    int base = vy * 33 + vx;
    atomicAdd(&bin[0 * PLANE + base], xv.x);
    atomicAdd(&bin[1 * PLANE + base], xv.y);
    atomicAdd(&bin[2 * PLANE + base], xv.z);
    atomicAdd(&bin[3 * PLANE + base], xv.w);
    atomicAdd(&bin[4 * PLANE + base], 1.0f);
  }
  __syncthreads();

  const int ui  = t >> 7;              // 0..3 -> ux = uxg*4+ui
  const int ux  = uxg * 4 + ui;
  const int rem = t & 127;
  const int vy  = rem >> 2;            // also uy in pass 2
  const int j   = rem & 3;

  // pass 1 (over vx), read from LDS bins
  {
    float a = 0.f, ac = 0.f;
    const float* Sp = bin + j * PLANE + vy * 33;
    const float* Cp = bin + 4 * PLANE + vy * 33;
#pragma unroll 8
    for (int vx = 0; vx < 32; ++vx) {
      float g = gxt[ux - vx + 31];
      a = fmaf(g, Sp[vx], a);
      if (j == 0) ac = fmaf(g, Cp[vx], ac);
    }
    T1[ui][vy][j] = a;
    if (j == 0) Tcc[ui][vy] = ac;
  }
  __syncthreads();

  // pass 2 (over vy) + finalize
  {
    const int uy = vy;
    float d = 0.f, rs = 0.f;
#pragma unroll 8
    for (int v = 0; v < 32; ++v) {
      float g = gyt[uy - v + 31];
      d  = fmaf(g, T1[ui][v][j], d);
      rs = fmaf(g, Tcc[ui][v], rs);
    }
    int p = (uy * 32 + ux) * DIM + q * 4 + j;
    out[p] = w[p] * (1.0f - rs) + d;
  }
}

extern "C" void kernel_launch(void* const* d_in, const int* in_sizes, int n_in,
                              void* d_out, int out_size, void* d_ws, size_t ws_size,
                              hipStream_t stream) {
  const float* x   = (const float*)d_in[0];   // [2048,128] f32
  const float* w   = (const float*)d_in[1];   // [1024,128] f32
  const int*   itp = (const int*)d_in[3];     // [1] i32 (meshgrid baked in)
  float* out = (float*)d_out;                 // [1024,128] f32

  unsigned long long* keys = (unsigned long long*)d_ws;  // 32 KB, fully written

  bmu_kernel<<<256, 1024, 0, stream>>>(x, w, keys);
  convgather_kernel<<<256, 512, 0, stream>>>(x, keys, w, itp, out);
}